// Round 3
// baseline (106.402 us; speedup 1.0000x reference)
//
#include <hip/hip_runtime.h>
#include <math.h>

__device__ __forceinline__ float frcp(float x) { return __builtin_amdgcn_rcpf(x); }

// Branchless Sutherland-Hodgman vs an AXIS-ALIGNED rect (box2's local frame).
// Each clip stage emits exactly 2 slots per input edge; placeholder points lie
// on the clip line so they telescope out of the shoelace sum (validated R2).
// Axis-aligned clip: d = +/-(coord - c) is 1 op, projection is a coordinate
// select, crossing needs a single fma for the free coordinate.

// Vertical clip (boundary x = C). GE: inside is x >= C, else x <= C.
template<int N, bool GE>
__device__ __forceinline__ void clipV(float C,
                                      const float (&ix)[N], const float (&iy)[N],
                                      float (&ox)[2 * N], float (&oy)[2 * N]) {
    float d[N]; bool in[N];
    #pragma unroll
    for (int k = 0; k < N; k++) {
        d[k] = GE ? (ix[k] - C) : (C - ix[k]);
        in[k] = d[k] >= 0.0f;
    }
    #pragma unroll
    for (int k = 0; k < N; k++) {
        const int kn = (k + 1) % N;
        float t  = d[k] * frcp(d[k] - d[kn]);
        float Cy = fmaf(t, iy[kn] - iy[k], iy[k]);
        bool cr = in[k] != in[kn];
        ox[2 * k]     = (cr || !in[k]) ? C : ix[k];
        oy[2 * k]     = cr ? Cy : iy[k];
        ox[2 * k + 1] = in[kn] ? ix[kn] : C;
        oy[2 * k + 1] = iy[kn];
    }
}

__global__ __launch_bounds__(256, 8) void iou3d_loss_kernel(
    const float* __restrict__ pred, const float* __restrict__ target,
    double* __restrict__ acc_out, int N)
{
    int i = blockIdx.x * blockDim.x + threadIdx.x;
    float val = 0.0f;
    if (i < N) {
        const float* b1 = pred   + (size_t)i * 7;
        const float* b2 = target + (size_t)i * 7;
        float x1 = b1[0], y1 = b1[1], z1 = b1[2], w1 = b1[3], h1 = b1[4], dz1 = b1[5], a1 = b1[6];
        float x2 = b2[0], y2 = b2[1], z2 = b2[2], w2 = b2[3], h2 = b2[4], dz2 = b2[5], a2 = b2[6];

        // epilogue scalars first (lets z/dz die early)
        float zo = fmaxf(fminf(z1 + 0.5f * dz1, z2 + 0.5f * dz2)
                       - fmaxf(z1 - 0.5f * dz1, z2 - 0.5f * dz2), 0.0f);
        float vol1 = w1 * h1 * dz1;
        float vol2 = w2 * h2 * dz2;

        // ---- box2 local frame: rotate by -a2 about (x2,y2) ----
        float sa = __sinf(a2), ca = __cosf(a2);
        float dxc = x1 - x2, dyc = y1 - y2;
        float tx =  dxc * ca + dyc * sa;
        float ty = -dxc * sa + dyc * ca;
        float ad = a1 - a2;
        float sd = __sinf(ad), cd = __cosf(ad);
        float hw1 = 0.5f * w1, hh1 = 0.5f * h1;
        float hw2 = 0.5f * w2, hh2 = 0.5f * h2;
        // rotated half-edge vectors of box1
        float ex = hw1 * cd, ey = hw1 * sd;    // R(ad)*(hw1,0)
        float fx = -hh1 * sd, fy = hh1 * cd;   // R(ad)*(0,hh1)
        // CCW corners
        float qx[4], qy[4];
        qx[0] = tx + ex + fx; qy[0] = ty + ey + fy;
        qx[1] = tx - ex + fx; qy[1] = ty - ey + fy;
        qx[2] = tx - ex - fx; qy[2] = ty - ey - fy;
        qx[3] = tx + ex - fx; qy[3] = ty + ey - fy;

        // ---- stage A: x >= -hw2 (4->8), stage B: x <= hw2 (8->16) ----
        float aX[8], aY[8];
        clipV<4, true>(-hw2, qx, qy, aX, aY);
        float bX[16], bY[16];
        clipV<8, false>(hw2, aX, aY, bX, bY);

        // ---- stage C: y >= -hh2 (16->32, streamed) into stage D: y <= hh2 + shoelace ----
        // Horizontal clips leave x unchanged, so raw x == clipped x everywhere.
        float acc = 0.0f;
        const float cC = -hh2, cD = hh2;

        // stage-C state for vertex 0 (saved for wrap)
        float dA = bY[0] + hh2; bool iA = dA >= 0.0f;
        float vAx = bX[0], vAy = iA ? bY[0] : cC;
        float d0s = dA; bool i0s = iA; float v0x = vAx, v0y = vAy;

        // stage-D stream state
        float dp = 0.f, pvx = 0.f, pvy = 0.f; bool pin = false;
        float opx = 0.f, opy = 0.f, ofx = 0.f, ofy = 0.f;
        float fsx = 0.f, fsy = 0.f;

        #define SINIT(RX, RY) do { \
            dp = cD - (RY); pin = dp >= 0.0f; \
            pvx = (RX); pvy = pin ? (RY) : cD; \
        } while (0)

        #define PUSH(RX, RY, FIRSTOUT) do { \
            float dv_ = cD - (RY); \
            bool inv_ = dv_ >= 0.0f; \
            float vvx_ = (RX), vvy_ = inv_ ? (RY) : cD; \
            float t_ = dp * frcp(dp - dv_); \
            float Cx_ = fmaf(t_, (RX) - pvx, pvx); \
            bool cr_ = (pin != inv_); \
            float q0x = cr_ ? Cx_ : pvx; \
            float q0y = cr_ ? cD : pvy; \
            if (FIRSTOUT) { ofx = q0x; ofy = q0y; } \
            else { acc = fmaf(opx, q0y, acc); acc = fmaf(-opy, q0x, acc); } \
            acc = fmaf(q0x, vvy_, acc); acc = fmaf(-q0y, vvx_, acc); \
            opx = vvx_; opy = vvy_; \
            dp = dv_; pvx = vvx_; pvy = vvy_; pin = inv_; \
        } while (0)

        #pragma unroll
        for (int k = 0; k < 16; k++) {
            const int kn = (k + 1) & 15;
            float dB, vBx, vBy; bool iB;
            if (kn == 0) {              // compile-time under full unroll
                dB = d0s; iB = i0s; vBx = v0x; vBy = v0y;
            } else {
                dB = bY[kn] + hh2;
                iB = dB >= 0.0f;
                vBx = bX[kn];
                vBy = iB ? bY[kn] : cC;
            }
            // stage-C edge (A,B): crossing has y = cC, x needs one fma
            float t  = dA * frcp(dA - dB);
            float Cx = fmaf(t, vBx - vAx, vAx);
            bool cr = (iA != iB);
            float r0x = cr ? Cx : vAx;
            float r0y = cr ? cC : vAy;
            float r1x = vBx, r1y = vBy;

            if (k == 0) {
                fsx = r0x; fsy = r0y;
                SINIT(r0x, r0y);
                PUSH(r1x, r1y, true);
            } else {
                PUSH(r0x, r0y, false);
                PUSH(r1x, r1y, false);
            }
            dA = dB; iA = iB; vAx = vBx; vAy = vBy;
        }
        // wrap edge back to first stage-C output, then close the cycle
        PUSH(fsx, fsy, false);
        acc = fmaf(opx, ofy, acc);
        acc = fmaf(-opy, ofx, acc);

        #undef PUSH
        #undef SINIT

        float area = fabsf(acc) * 0.5f;
        float inter3d = area * zo;
        float union3d = vol1 + vol2 - inter3d;
        val = 1.0f - inter3d / union3d;
    }

    // ---- block reduction -> double atomic ----
    #pragma unroll
    for (int off = 32; off > 0; off >>= 1)
        val += __shfl_down(val, off, 64);
    __shared__ float wsum[4];
    int lane = threadIdx.x & 63, wid = threadIdx.x >> 6;
    if (lane == 0) wsum[wid] = val;
    __syncthreads();
    if (threadIdx.x == 0) {
        float s = wsum[0] + wsum[1] + wsum[2] + wsum[3];
        atomicAdd(acc_out, (double)s);
    }
}

__global__ void iou3d_finalize_kernel(const double* __restrict__ acc,
                                      float* __restrict__ out, int N)
{
    out[0] = (float)(acc[0] / (double)N);
}

extern "C" void kernel_launch(void* const* d_in, const int* in_sizes, int n_in,
                              void* d_out, int out_size, void* d_ws, size_t ws_size,
                              hipStream_t stream) {
    const float* pred   = (const float*)d_in[0];
    const float* target = (const float*)d_in[1];
    int N = in_sizes[0] / 7;
    double* acc = (double*)d_ws;

    hipMemsetAsync(d_ws, 0, sizeof(double), stream);

    int block = 256;
    int grid = (N + block - 1) / block;
    iou3d_loss_kernel<<<grid, block, 0, stream>>>(pred, target, acc, N);
    iou3d_finalize_kernel<<<1, 1, 0, stream>>>(acc, (float*)d_out, N);
}

// Round 4
// 63.666 us; speedup vs baseline: 1.6713x; 1.6713x over previous
//
#include <hip/hip_runtime.h>
#include <math.h>

__device__ __forceinline__ float frcp(float x) { return __builtin_amdgcn_rcpf(x); }

// Branchless Sutherland-Hodgman vs an AXIS-ALIGNED rect (box2's local frame).
// Each clip stage emits exactly 2 slots per input edge; placeholder points lie
// on the clip line so they telescope out of the shoelace sum (validated R2).
// Axis-aligned clip: d = +/-(coord - c) is 1 op, projection is a coordinate
// select, crossing needs a single fma for the free coordinate.

// Vertical clip (boundary x = C). GE: inside is x >= C, else x <= C.
template<int N, bool GE>
__device__ __forceinline__ void clipV(float C,
                                      const float (&ix)[N], const float (&iy)[N],
                                      float (&ox)[2 * N], float (&oy)[2 * N]) {
    float d[N]; bool in[N];
    #pragma unroll
    for (int k = 0; k < N; k++) {
        d[k] = GE ? (ix[k] - C) : (C - ix[k]);
        in[k] = d[k] >= 0.0f;
    }
    #pragma unroll
    for (int k = 0; k < N; k++) {
        const int kn = (k + 1) % N;
        float t  = d[k] * frcp(d[k] - d[kn]);
        float Cy = fmaf(t, iy[kn] - iy[k], iy[k]);
        bool cr = in[k] != in[kn];
        ox[2 * k]     = (cr || !in[k]) ? C : ix[k];
        oy[2 * k]     = cr ? Cy : iy[k];
        ox[2 * k + 1] = in[kn] ? ix[kn] : C;
        oy[2 * k + 1] = iy[kn];
    }
}

__global__ __launch_bounds__(256) void iou3d_loss_kernel(
    const float* __restrict__ pred, const float* __restrict__ target,
    double* __restrict__ acc_out, int N)
{
    int i = blockIdx.x * blockDim.x + threadIdx.x;
    float val = 0.0f;
    if (i < N) {
        const float* b1 = pred   + (size_t)i * 7;
        const float* b2 = target + (size_t)i * 7;
        float x1 = b1[0], y1 = b1[1], z1 = b1[2], w1 = b1[3], h1 = b1[4], dz1 = b1[5], a1 = b1[6];
        float x2 = b2[0], y2 = b2[1], z2 = b2[2], w2 = b2[3], h2 = b2[4], dz2 = b2[5], a2 = b2[6];

        // epilogue scalars first (lets z/dz die early)
        float zo = fmaxf(fminf(z1 + 0.5f * dz1, z2 + 0.5f * dz2)
                       - fmaxf(z1 - 0.5f * dz1, z2 - 0.5f * dz2), 0.0f);
        float vol1 = w1 * h1 * dz1;
        float vol2 = w2 * h2 * dz2;

        // ---- box2 local frame: rotate by -a2 about (x2,y2) ----
        float sa = __sinf(a2), ca = __cosf(a2);
        float dxc = x1 - x2, dyc = y1 - y2;
        float tx =  dxc * ca + dyc * sa;
        float ty = -dxc * sa + dyc * ca;
        float ad = a1 - a2;
        float sd = __sinf(ad), cd = __cosf(ad);
        float hw1 = 0.5f * w1, hh1 = 0.5f * h1;
        float hw2 = 0.5f * w2, hh2 = 0.5f * h2;
        // rotated half-edge vectors of box1
        float ex = hw1 * cd, ey = hw1 * sd;    // R(ad)*(hw1,0)
        float fx = -hh1 * sd, fy = hh1 * cd;   // R(ad)*(0,hh1)
        // CCW corners
        float qx[4], qy[4];
        qx[0] = tx + ex + fx; qy[0] = ty + ey + fy;
        qx[1] = tx - ex + fx; qy[1] = ty - ey + fy;
        qx[2] = tx - ex - fx; qy[2] = ty - ey - fy;
        qx[3] = tx + ex - fx; qy[3] = ty + ey - fy;

        // ---- stage A: x >= -hw2 (4->8), stage B: x <= hw2 (8->16) ----
        float aX[8], aY[8];
        clipV<4, true>(-hw2, qx, qy, aX, aY);
        float bX[16], bY[16];
        clipV<8, false>(hw2, aX, aY, bX, bY);

        // ---- stage C: y >= -hh2 (16->32, streamed) into stage D: y <= hh2 + shoelace ----
        // Horizontal clips leave x unchanged, so raw x == clipped x everywhere.
        float acc = 0.0f;
        const float cC = -hh2, cD = hh2;

        // stage-C state for vertex 0 (saved for wrap)
        float dA = bY[0] + hh2; bool iA = dA >= 0.0f;
        float vAx = bX[0], vAy = iA ? bY[0] : cC;
        float d0s = dA; bool i0s = iA; float v0x = vAx, v0y = vAy;

        // stage-D stream state
        float dp = 0.f, pvx = 0.f, pvy = 0.f; bool pin = false;
        float opx = 0.f, opy = 0.f, ofx = 0.f, ofy = 0.f;
        float fsx = 0.f, fsy = 0.f;

        #define SINIT(RX, RY) do { \
            dp = cD - (RY); pin = dp >= 0.0f; \
            pvx = (RX); pvy = pin ? (RY) : cD; \
        } while (0)

        #define PUSH(RX, RY, FIRSTOUT) do { \
            float dv_ = cD - (RY); \
            bool inv_ = dv_ >= 0.0f; \
            float vvx_ = (RX), vvy_ = inv_ ? (RY) : cD; \
            float t_ = dp * frcp(dp - dv_); \
            float Cx_ = fmaf(t_, (RX) - pvx, pvx); \
            bool cr_ = (pin != inv_); \
            float q0x = cr_ ? Cx_ : pvx; \
            float q0y = cr_ ? cD : pvy; \
            if (FIRSTOUT) { ofx = q0x; ofy = q0y; } \
            else { acc = fmaf(opx, q0y, acc); acc = fmaf(-opy, q0x, acc); } \
            acc = fmaf(q0x, vvy_, acc); acc = fmaf(-q0y, vvx_, acc); \
            opx = vvx_; opy = vvy_; \
            dp = dv_; pvx = vvx_; pvy = vvy_; pin = inv_; \
        } while (0)

        #pragma unroll
        for (int k = 0; k < 16; k++) {
            const int kn = (k + 1) & 15;
            float dB, vBx, vBy; bool iB;
            if (kn == 0) {              // compile-time under full unroll
                dB = d0s; iB = i0s; vBx = v0x; vBy = v0y;
            } else {
                dB = bY[kn] + hh2;
                iB = dB >= 0.0f;
                vBx = bX[kn];
                vBy = iB ? bY[kn] : cC;
            }
            // stage-C edge (A,B): crossing has y = cC, x needs one fma
            float t  = dA * frcp(dA - dB);
            float Cx = fmaf(t, vBx - vAx, vAx);
            bool cr = (iA != iB);
            float r0x = cr ? Cx : vAx;
            float r0y = cr ? cC : vAy;
            float r1x = vBx, r1y = vBy;

            if (k == 0) {
                fsx = r0x; fsy = r0y;
                SINIT(r0x, r0y);
                PUSH(r1x, r1y, true);
            } else {
                PUSH(r0x, r0y, false);
                PUSH(r1x, r1y, false);
            }
            dA = dB; iA = iB; vAx = vBx; vAy = vBy;
        }
        // wrap edge back to first stage-C output, then close the cycle
        PUSH(fsx, fsy, false);
        acc = fmaf(opx, ofy, acc);
        acc = fmaf(-opy, ofx, acc);

        #undef PUSH
        #undef SINIT

        float area = fabsf(acc) * 0.5f;
        float inter3d = area * zo;
        float union3d = vol1 + vol2 - inter3d;
        val = 1.0f - inter3d / union3d;
    }

    // ---- block reduction -> double atomic ----
    #pragma unroll
    for (int off = 32; off > 0; off >>= 1)
        val += __shfl_down(val, off, 64);
    __shared__ float wsum[4];
    int lane = threadIdx.x & 63, wid = threadIdx.x >> 6;
    if (lane == 0) wsum[wid] = val;
    __syncthreads();
    if (threadIdx.x == 0) {
        float s = wsum[0] + wsum[1] + wsum[2] + wsum[3];
        atomicAdd(acc_out, (double)s);
    }
}

__global__ void iou3d_finalize_kernel(const double* __restrict__ acc,
                                      float* __restrict__ out, int N)
{
    out[0] = (float)(acc[0] / (double)N);
}

extern "C" void kernel_launch(void* const* d_in, const int* in_sizes, int n_in,
                              void* d_out, int out_size, void* d_ws, size_t ws_size,
                              hipStream_t stream) {
    const float* pred   = (const float*)d_in[0];
    const float* target = (const float*)d_in[1];
    int N = in_sizes[0] / 7;
    double* acc = (double*)d_ws;

    hipMemsetAsync(d_ws, 0, sizeof(double), stream);

    int block = 256;
    int grid = (N + block - 1) / block;
    iou3d_loss_kernel<<<grid, block, 0, stream>>>(pred, target, acc, N);
    iou3d_finalize_kernel<<<1, 1, 0, stream>>>(acc, (float*)d_out, N);
}

// Round 5
// 61.870 us; speedup vs baseline: 1.7198x; 1.0290x over previous
//
#include <hip/hip_runtime.h>
#include <math.h>

__device__ __forceinline__ float frcp(float x) { return __builtin_amdgcn_rcpf(x); }

// Exact area of (CCW polygon edge decomposition) ∩ axis-aligned box
// [-hw,hw] x [-hh,hh], via the coverage identity:
//   1_P(x,y) = sum_e sigma_e * [x in xrange(e)] * [y <= y_e(x)],  sigma_e = -sign(dx)
// => Area(P ∩ B) = sum_e sigma_e * ( ∫ clamp(y_e(x), Y0, Y1) dx  -  Y0 * w_e )
// with the integral over the edge's x-range clipped to [X0,X1].
// Branchless; safe reciprocals floored at 1e-20 keep all intermediates finite.
__device__ __forceinline__ float edge_area(float px, float py, float qx, float qy,
                                           float hw, float hh) {
    const float Y0 = -hh, Y1 = hh;
    float dx = qx - px, dy = qy - py;
    float lo = fmaxf(fminf(px, qx), -hw);
    float hi = fminf(fmaxf(px, qx),  hw);
    float w  = hi - lo;                      // <=0 -> no contribution
    // safe slopes (keep sign, avoid inf/NaN)
    float dys = (fabsf(dy) > 1e-20f) ? dy : ((dy >= 0.f) ? 1e-20f : -1e-20f);
    float dxs = (fabsf(dx) > 1e-20f) ? dx : ((dx >= 0.f) ? 1e-20f : -1e-20f);
    float xdy = dx * frcp(dys);              // dx/dy
    float m   = dy * frcp(dxs);              // dy/dx
    // x-coords where the edge line crosses y = Y0 / Y1 (may be huge; clamped next)
    float xa = fmaf(Y0 - py, xdy, px);
    float xb = fmaf(Y1 - py, xdy, px);
    float s0 = fminf(xa, xb), s1 = fmaxf(xa, xb);
    float u0 = fminf(fmaxf(s0, lo), hi);
    float u1 = fminf(fmaxf(s1, lo), hi);
    float yu0 = fmaf(m, u0 - px, py);
    float yu1 = fmaf(m, u1 - px, py);
    yu0 = fminf(fmaxf(yu0, Y0), Y1);
    yu1 = fminf(fmaxf(yu1, Y0), Y1);
    // plateau values: left side is Y0 when slope >= 0 else Y1
    bool mpos = (dy >= 0.f) == (dx >= 0.f);
    float YL = mpos ? Y0 : Y1;
    float YR = mpos ? Y1 : Y0;
    float integral = YL * (u0 - lo)
                   + 0.5f * (yu0 + yu1) * (u1 - u0)
                   + YR * (hi - u1);
    float contrib = integral - Y0 * w;
    float res = (dx > 0.f) ? -contrib : contrib;   // sigma = -sign(dx)
    return (w > 0.f) ? res : 0.f;
}

__global__ __launch_bounds__(256) void iou3d_loss_kernel(
    const float* __restrict__ pred, const float* __restrict__ target,
    double* __restrict__ acc_out, int N)
{
    int i = blockIdx.x * blockDim.x + threadIdx.x;
    float val = 0.0f;
    if (i < N) {
        const float* b1 = pred   + (size_t)i * 7;
        const float* b2 = target + (size_t)i * 7;
        float x1 = b1[0], y1 = b1[1], z1 = b1[2], w1 = b1[3], h1 = b1[4], dz1 = b1[5], a1 = b1[6];
        float x2 = b2[0], y2 = b2[1], z2 = b2[2], w2 = b2[3], h2 = b2[4], dz2 = b2[5], a2 = b2[6];

        // z-overlap + volumes (lets z/dz registers die early)
        float zo = fmaxf(fminf(z1 + 0.5f * dz1, z2 + 0.5f * dz2)
                       - fmaxf(z1 - 0.5f * dz1, z2 - 0.5f * dz2), 0.0f);
        float vol1 = w1 * h1 * dz1;
        float vol2 = w2 * h2 * dz2;

        // ---- box2 local frame: rotate by -a2 about (x2,y2) ----
        float sa = __sinf(a2), ca = __cosf(a2);
        float dxc = x1 - x2, dyc = y1 - y2;
        float tx =  dxc * ca + dyc * sa;
        float ty = -dxc * sa + dyc * ca;
        float ad = a1 - a2;
        float sd = __sinf(ad), cd = __cosf(ad);
        float hw1 = 0.5f * w1, hh1 = 0.5f * h1;
        float hw2 = 0.5f * w2, hh2 = 0.5f * h2;
        float ex = hw1 * cd, ey = hw1 * sd;     // R(ad)*(hw1,0)
        float fx = -hh1 * sd, fy = hh1 * cd;    // R(ad)*(0,hh1)
        // CCW corners of box1 in box2's frame
        float q0x = tx + ex + fx, q0y = ty + ey + fy;
        float q1x = tx - ex + fx, q1y = ty - ey + fy;
        float q2x = tx - ex - fx, q2y = ty - ey - fy;
        float q3x = tx + ex - fx, q3y = ty + ey - fy;

        // ---- 4 independent per-edge coverage integrals ----
        float area = edge_area(q0x, q0y, q1x, q1y, hw2, hh2)
                   + edge_area(q1x, q1y, q2x, q2y, hw2, hh2)
                   + edge_area(q2x, q2y, q3x, q3y, hw2, hh2)
                   + edge_area(q3x, q3y, q0x, q0y, hw2, hh2);
        area = fabsf(area);

        float inter3d = area * zo;
        float union3d = vol1 + vol2 - inter3d;
        val = 1.0f - inter3d / union3d;
    }

    // ---- block reduction -> double atomic ----
    #pragma unroll
    for (int off = 32; off > 0; off >>= 1)
        val += __shfl_down(val, off, 64);
    __shared__ float wsum[4];
    int lane = threadIdx.x & 63, wid = threadIdx.x >> 6;
    if (lane == 0) wsum[wid] = val;
    __syncthreads();
    if (threadIdx.x == 0) {
        float s = wsum[0] + wsum[1] + wsum[2] + wsum[3];
        atomicAdd(acc_out, (double)s);
    }
}

__global__ void iou3d_finalize_kernel(const double* __restrict__ acc,
                                      float* __restrict__ out, int N)
{
    out[0] = (float)(acc[0] / (double)N);
}

extern "C" void kernel_launch(void* const* d_in, const int* in_sizes, int n_in,
                              void* d_out, int out_size, void* d_ws, size_t ws_size,
                              hipStream_t stream) {
    const float* pred   = (const float*)d_in[0];
    const float* target = (const float*)d_in[1];
    int N = in_sizes[0] / 7;
    double* acc = (double*)d_ws;

    hipMemsetAsync(d_ws, 0, sizeof(double), stream);

    int block = 256;
    int grid = (N + block - 1) / block;
    iou3d_loss_kernel<<<grid, block, 0, stream>>>(pred, target, acc, N);
    iou3d_finalize_kernel<<<1, 1, 0, stream>>>(acc, (float*)d_out, N);
}

// Round 6
// 31.825 us; speedup vs baseline: 3.3434x; 1.9441x over previous
//
#include <hip/hip_runtime.h>
#include <math.h>

__device__ __forceinline__ float frcp(float x) { return __builtin_amdgcn_rcpf(x); }

// Exact area of CCW polygon ∩ axis-aligned box [-hw,hw]x[-hh,hh] via the
// per-edge coverage identity (validated R5, absmax 0 vs jax reference):
//   Area = sum_e sigma_e * ( ∫ clamp(y_e(x), Y0, Y1) dx - Y0 * w_e ),
// integral over the edge's x-range clipped to the box's x-slab.
__device__ __forceinline__ float edge_area(float px, float py, float qx, float qy,
                                           float hw, float hh) {
    const float Y0 = -hh, Y1 = hh;
    float dx = qx - px, dy = qy - py;
    float lo = fmaxf(fminf(px, qx), -hw);
    float hi = fminf(fmaxf(px, qx),  hw);
    float w  = hi - lo;
    float dys = (fabsf(dy) > 1e-20f) ? dy : ((dy >= 0.f) ? 1e-20f : -1e-20f);
    float dxs = (fabsf(dx) > 1e-20f) ? dx : ((dx >= 0.f) ? 1e-20f : -1e-20f);
    float xdy = dx * frcp(dys);
    float m   = dy * frcp(dxs);
    float xa = fmaf(Y0 - py, xdy, px);
    float xb = fmaf(Y1 - py, xdy, px);
    float s0 = fminf(xa, xb), s1 = fmaxf(xa, xb);
    float u0 = fminf(fmaxf(s0, lo), hi);
    float u1 = fminf(fmaxf(s1, lo), hi);
    float yu0 = fmaf(m, u0 - px, py);
    float yu1 = fmaf(m, u1 - px, py);
    yu0 = fminf(fmaxf(yu0, Y0), Y1);
    yu1 = fminf(fmaxf(yu1, Y0), Y1);
    bool mpos = (dy >= 0.f) == (dx >= 0.f);
    float YL = mpos ? Y0 : Y1;
    float YR = mpos ? Y1 : Y0;
    float integral = YL * (u0 - lo)
                   + 0.5f * (yu0 + yu1) * (u1 - u0)
                   + YR * (hi - u1);
    float contrib = integral - Y0 * w;
    float res = (dx > 0.f) ? -contrib : contrib;
    return (w > 0.f) ? res : 0.f;
}

// one element: b1/b2 are 7 floats each -> 1 - iou3d
__device__ __forceinline__ float elem_loss(const float b1[7], const float b2[7]) {
    float x1 = b1[0], y1 = b1[1], z1 = b1[2], w1 = b1[3], h1 = b1[4], dz1 = b1[5], a1 = b1[6];
    float x2 = b2[0], y2 = b2[1], z2 = b2[2], w2 = b2[3], h2 = b2[4], dz2 = b2[5], a2 = b2[6];

    float zo = fmaxf(fminf(z1 + 0.5f * dz1, z2 + 0.5f * dz2)
                   - fmaxf(z1 - 0.5f * dz1, z2 - 0.5f * dz2), 0.0f);
    float vol1 = w1 * h1 * dz1;
    float vol2 = w2 * h2 * dz2;

    float sa = __sinf(a2), ca = __cosf(a2);
    float dxc = x1 - x2, dyc = y1 - y2;
    float tx =  dxc * ca + dyc * sa;
    float ty = -dxc * sa + dyc * ca;
    float ad = a1 - a2;
    float sd = __sinf(ad), cd = __cosf(ad);
    float hw1 = 0.5f * w1, hh1 = 0.5f * h1;
    float hw2 = 0.5f * w2, hh2 = 0.5f * h2;
    float ex = hw1 * cd, ey = hw1 * sd;
    float fx = -hh1 * sd, fy = hh1 * cd;
    float q0x = tx + ex + fx, q0y = ty + ey + fy;
    float q1x = tx - ex + fx, q1y = ty - ey + fy;
    float q2x = tx - ex - fx, q2y = ty - ey - fy;
    float q3x = tx + ex - fx, q3y = ty + ey - fy;

    float area = edge_area(q0x, q0y, q1x, q1y, hw2, hh2)
               + edge_area(q1x, q1y, q2x, q2y, hw2, hh2)
               + edge_area(q2x, q2y, q3x, q3y, hw2, hh2)
               + edge_area(q3x, q3y, q0x, q0y, hw2, hh2);
    area = fabsf(area);

    float inter3d = area * zo;
    float union3d = vol1 + vol2 - inter3d;
    return 1.0f - inter3d / union3d;
}

#define EPT 4  // elements per thread

__global__ __launch_bounds__(256) void iou3d_loss_kernel(
    const float* __restrict__ pred, const float* __restrict__ target,
    double* __restrict__ acc_out, int N)
{
    int t = blockIdx.x * blockDim.x + threadIdx.x;
    long base = (long)t * EPT;
    float val = 0.0f;

    if (base + EPT <= N) {
        // 4 elements = 28 contiguous floats = 7 x float4 (16B-aligned: 112B stride)
        float a[28], b[28];
        const float4* p4 = (const float4*)(pred   + base * 7);
        const float4* t4 = (const float4*)(target + base * 7);
        #pragma unroll
        for (int k = 0; k < 7; k++) {
            float4 va = p4[k];
            a[4 * k] = va.x; a[4 * k + 1] = va.y; a[4 * k + 2] = va.z; a[4 * k + 3] = va.w;
            float4 vb = t4[k];
            b[4 * k] = vb.x; b[4 * k + 1] = vb.y; b[4 * k + 2] = vb.z; b[4 * k + 3] = vb.w;
        }
        #pragma unroll
        for (int k = 0; k < EPT; k++)
            val += elem_loss(&a[7 * k], &b[7 * k]);
    } else if (base < N) {
        for (long e = base; e < N; e++) {
            float a[7], b[7];
            #pragma unroll
            for (int k = 0; k < 7; k++) { a[k] = pred[e * 7 + k]; b[k] = target[e * 7 + k]; }
            val += elem_loss(a, b);
        }
    }

    // ---- block reduction -> double atomic ----
    #pragma unroll
    for (int off = 32; off > 0; off >>= 1)
        val += __shfl_down(val, off, 64);
    __shared__ float wsum[4];
    int lane = threadIdx.x & 63, wid = threadIdx.x >> 6;
    if (lane == 0) wsum[wid] = val;
    __syncthreads();
    if (threadIdx.x == 0) {
        float s = wsum[0] + wsum[1] + wsum[2] + wsum[3];
        atomicAdd(acc_out, (double)s);
    }
}

__global__ void iou3d_finalize_kernel(const double* __restrict__ acc,
                                      float* __restrict__ out, int N)
{
    out[0] = (float)(acc[0] / (double)N);
}

extern "C" void kernel_launch(void* const* d_in, const int* in_sizes, int n_in,
                              void* d_out, int out_size, void* d_ws, size_t ws_size,
                              hipStream_t stream) {
    const float* pred   = (const float*)d_in[0];
    const float* target = (const float*)d_in[1];
    int N = in_sizes[0] / 7;
    double* acc = (double*)d_ws;

    hipMemsetAsync(d_ws, 0, sizeof(double), stream);

    int block = 256;
    int threads = (N + EPT - 1) / EPT;
    int grid = (threads + block - 1) / block;
    iou3d_loss_kernel<<<grid, block, 0, stream>>>(pred, target, acc, N);
    iou3d_finalize_kernel<<<1, 1, 0, stream>>>(acc, (float*)d_out, N);
}